// Round 13
// baseline (635.484 us; speedup 1.0000x reference)
//
#include <hip/hip_runtime.h>

// Billeh column GLIF forward — persistent kernel, split-phase hierarchical
// barrier (R10 structure), 98 blocks x 1024 neurons.
//
// R11 post-mortem: flag-vector barrier regressed (+2us/step) — 196 leader
// waves x 256 flag loads per poll is a MALL traffic storm; R10's hierarchical
// RMW (25 serialized arrivals/group) was better. Reverted. This round halves
// the barrier's serialized-RMW term by halving the block count: BKN=1024
// neurons/block -> 98 blocks, 13 arrivals/group. Per-thread edge work doubles
// (~20 in-register mask tests — still overlapped/cheap); edge preload grows
// to 6 uint4+float4 quads (~95 VGPR, within the 128 cap).
// (R12 bench was an infra failure — container died before measuring; kernel
// re-audited for hang risks: barrier group sums = nblk, VGPR < cap, LDS OK.)

constexpr int RR  = 4;
constexpr int BS  = 1024;               // threads per block
constexpr int BKN = 1024;               // neurons per block (bucket size)
constexpr int BSH = 10;                 // log2(BKN)
constexpr int NCH = 512;                // partition chunks
constexpr int NQ  = 6;                  // preloaded quads per thread

// ---------------- pass 1: per-chunk bucket histogram (+ misc zeroing) ------
__global__ void count_kernel(const int* __restrict__ post, int* __restrict__ ghist,
                             unsigned long long* __restrict__ mA,
                             unsigned long long* __restrict__ mB,
                             unsigned* __restrict__ barr,
                             int E, int CH, int NBK, int nmask, int nbar) {
    __shared__ int h[256];                       // NBK <= 256
    for (int i = threadIdx.x; i < NBK; i += blockDim.x) h[i] = 0;
    __syncthreads();
    const int b = blockIdx.x, lo = b * CH, hi = min(lo + CH, E);
    for (int e = lo + threadIdx.x; e < hi; e += blockDim.x)
        atomicAdd(&h[post[e] >> BSH], 1);        // LDS atomic: block-local
    __syncthreads();
    for (int i = threadIdx.x; i < NBK; i += blockDim.x)
        ghist[i * NCH + b] = h[i];               // bucket-major
    int g = blockIdx.x * blockDim.x + threadIdx.x;
    int gs = gridDim.x * blockDim.x;
    for (int i = g; i < nmask; i += gs) { mA[i] = 0ull; mB[i] = 0ull; }
    for (int i = g; i < nbar; i += gs) barr[i] = 0u;
}

// ---------------- pass 2a: per-bucket exclusive scan over chunks -----------
__global__ void scanA_kernel(int* __restrict__ ghist, int* __restrict__ rtot,
                             int* __restrict__ ptot) {
    __shared__ int s[NCH];
    const int i = blockIdx.x, tid = threadIdx.x;
    int v = ghist[i * NCH + tid];
    s[tid] = v;
    __syncthreads();
    for (int off = 1; off < NCH; off <<= 1) {
        int t = (tid >= off) ? s[tid - off] : 0;
        __syncthreads();
        s[tid] += t;
        __syncthreads();
    }
    ghist[i * NCH + tid] = s[tid] - v;           // within-bucket exclusive
    if (tid == NCH - 1) {
        int tot = s[tid];
        rtot[i] = tot;
        ptot[i] = (tot + 3) & ~3;                // pad to x4 records
    }
}

// ---------------- pass 2b: scan padded totals -> bstart; zero pad slots ----
__global__ void scanB_kernel(const int* __restrict__ rtot, const int* __restrict__ ptot,
                             int* __restrict__ bstart,
                             unsigned* __restrict__ epack, float* __restrict__ ew,
                             int NBK) {
    __shared__ int s[256];
    const int tid = threadIdx.x;
    int v = (tid < NBK) ? ptot[tid] : 0;
    s[tid] = v;
    __syncthreads();
    for (int off = 1; off < 256; off <<= 1) {
        int t = (tid >= off) ? s[tid - off] : 0;
        __syncthreads();
        s[tid] += t;
        __syncthreads();
    }
    if (tid < NBK) bstart[tid] = s[tid] - v;
    if (tid == NBK - 1) bstart[NBK] = s[tid];
    __syncthreads();
    if (tid < NBK) {                              // zero the <=3 pad records
        int base = bstart[tid];
        for (int k = base + rtot[tid]; k < base + ptot[tid]; ++k) {
            epack[k] = 0u; ew[k] = 0.f;           // pre=0,w=0 -> harmless
        }
    }
}

// ---------------- pass 3: fill with block-local LDS cursors ----------------
// record: epack = pre(18b) | rc<<18 | lidx<<20 ; ew = weight
__global__ void fill_kernel(const int* __restrict__ pre, const int* __restrict__ post,
                            const int* __restrict__ rc, const float* __restrict__ w,
                            const int* __restrict__ ghist, const int* __restrict__ bstart,
                            unsigned* __restrict__ epack, float* __restrict__ ew,
                            int E, int CH, int NBK) {
    __shared__ int cur[256];
    const int b = blockIdx.x;
    for (int i = threadIdx.x; i < NBK; i += blockDim.x)
        cur[i] = bstart[i] + ghist[i * NCH + b];
    __syncthreads();
    const int lo = b * CH, hi = min(lo + CH, E);
    for (int e = lo + threadIdx.x; e < hi; e += blockDim.x) {
        int pn = post[e];
        int k = atomicAdd(&cur[pn >> BSH], 1);   // LDS atomic: block-local
        epack[k] = (unsigned)pre[e] | ((unsigned)rc[e] << 18)
                 | ((unsigned)(pn & (BKN - 1)) << 20);
        ew[k] = w[e];
    }
}

// ---------------- persistent sim ----------------
__device__ __forceinline__ void test4(const uint4 pk, const float4 wv,
                                      const unsigned long long* smask,
                                      float* sacc) {
    unsigned a = pk.x & 0x3FFFFu, b = pk.y & 0x3FFFFu;
    unsigned c = pk.z & 0x3FFFFu, d = pk.w & 0x3FFFFu;
    if ((smask[a >> 6] >> (a & 63)) & 1ull) atomicAdd(&sacc[pk.x >> 18], wv.x);
    if ((smask[b >> 6] >> (b & 63)) & 1ull) atomicAdd(&sacc[pk.y >> 18], wv.y);
    if ((smask[c >> 6] >> (c & 63)) & 1ull) atomicAdd(&sacc[pk.z >> 18], wv.z);
    if ((smask[d >> 6] >> (d & 63)) & 1ull) atomicAdd(&sacc[pk.w >> 18], wv.w);
}

__global__ void __launch_bounds__(BS, 4)
sim_kernel(const float4* __restrict__ x_ext4,
           const float* __restrict__ v0,  const float* __restrict__ v_th,
           const float* __restrict__ v_rst, const float* __restrict__ t_rf,
           const float* __restrict__ decay, const float* __restrict__ curf,
           const float* __restrict__ e_l,
           const float2* __restrict__ aamps, const float2* __restrict__ adec,
           const float* __restrict__ syn_d4, const float* __restrict__ psc_i4,
           const uint4* __restrict__ epack4, const float4* __restrict__ ew4,
           const int* __restrict__ bstart,
           unsigned long long* __restrict__ mA, unsigned long long* __restrict__ mB,
           unsigned* __restrict__ barr,
           float* __restrict__ out, int N, int nmask, int T)
{
    extern __shared__ unsigned long long sdyn[];
    unsigned long long* smask = sdyn;            // nmask u64 (12.5 KB)
    float* sacc = (float*)(sdyn + nmask);        // BKN*4 floats (16 KB)
    const int tid = threadIdx.x;
    const int n = blockIdx.x * BKN + tid;        // one neuron per thread
    const bool own = n < N;
    const unsigned nblk = gridDim.x;

    // ---- per-neuron state + params: registers for the whole run ----
    float psc0 = 0.f, psc1 = 0.f, psc2 = 0.f, psc3 = 0.f;
    float pr0 = 0.f, pr1 = 0.f, pr2 = 0.f, pr3 = 0.f;
    float vv = 0.f, rr_ = 0.f, zz = 0.f, a0 = 0.f, a1 = 0.f;
    float vth = 1.f, dvr = 0.f, trf = 0.f, dec = 0.f, cf = 0.f, el = 0.f;
    float aa0 = 0.f, aa1 = 0.f, ad0 = 0.f, ad1 = 0.f;
    if (own) {
        vv  = v0[n];
        vth = v_th[n];  dvr = v_rst[n] - vth;
        trf = t_rf[n];  dec = decay[n];
        cf  = curf[n];  el  = e_l[n];
        float2 aa = aamps[n]; aa0 = aa.x; aa1 = aa.y;
        float2 ad = adec[n];  ad0 = ad.x; ad1 = ad.y;
    }
    const float sd0 = syn_d4[0], sd1 = syn_d4[1], sd2 = syn_d4[2], sd3 = syn_d4[3];
    const float pi0 = psc_i4[0], pi1 = psc_i4[1], pi2 = psc_i4[2], pi3 = psc_i4[3];

    // ---- preload this thread's edges into REGISTERS (constant across t) ----
    const int q_lo = bstart[blockIdx.x] >> 2;    // 4-aligned by construction
    const int q_hi = bstart[blockIdx.x + 1] >> 2;
    const uint4 z4 = make_uint4(0u, 0u, 0u, 0u);
    const float4 zf = make_float4(0.f, 0.f, 0.f, 0.f);
    uint4 q[NQ]; float4 w[NQ];
#pragma unroll
    for (int k = 0; k < NQ; ++k) {
        int idx = q_lo + tid + k * BS;
        q[k] = (idx < q_hi) ? epack4[idx] : z4;
        w[k] = (idx < q_hi) ? ew4[idx] : zf;
    }
    const bool overflow = (q_hi - q_lo) > NQ * BS;   // ~never (needs +28 sigma)

    const int g = blockIdx.x & 7;
    const unsigned gsize = (nblk - (unsigned)g + 7u) >> 3;

    // ---- prologue: zero LDS mask + accumulators; prefetch x(0) ----
    for (int i = tid; i < nmask; i += BS) smask[i] = 0ull;
#pragma unroll
    for (int j = 0; j < RR; ++j) sacc[tid + j * BS] = 0.f;
    float4 xt = own ? x_ext4[n] : zf;
    int anyspk = 0;
    __syncthreads();

    for (int t = 0; t < T; ++t) {
        // ======== Phase A: spike decision (OLD state only) + publish ========
        float nz = 0.f;
        if (own) {
            float npc0 = psc0 * sd0 + sd0 * pr0;   // OLD psc_rise, DT=1
            float npc1 = psc1 * sd1 + sd1 * pr1;
            float npc2 = psc2 * sd2 + sd2 * pr2;
            float npc3 = psc3 * sd3 + sd3 * pr3;
            float in_cur = npc0 + npc1 + npc2 + npc3;
            float asum = a0 + a1;                // OLD asc sum
            float nv = dec * vv + cf * (in_cur + asum + el) + zz * dvr;
            nz = (nv > vth) ? 1.f : 0.f;
            if (rr_ > 0.f) nz = 0.f;             // refractory mask (OLD r)
            rr_ = fmaxf(rr_ - 1.f + nz * trf, 0.f);
            a0 = ad0 * a0 + zz * aa0;            // asc update uses OLD z
            a1 = ad1 * a1 + zz * aa1;
            psc0 = npc0; psc1 = npc1; psc2 = npc2; psc3 = npc3;
            vv = nv;
        }
        const bool lastT = (t + 1 >= T);

        // publish mask(t) word (uncached store; one per wave)
        unsigned long long bal = __ballot(nz > 0.f);
        if (!lastT) {
            unsigned long long* gmo = (t & 1) ? mB : mA;
            if (own && (tid & 63) == 0)
                __hip_atomic_store(&gmo[n >> 6], bal, __ATOMIC_RELAXED,
                                   __HIP_MEMORY_SCOPE_AGENT);
            asm volatile("s_waitcnt vmcnt(0)" ::: "memory");
        }
        __syncthreads();                          // S1: all mask stores drained

        // non-blocking ARRIVAL (release chain completes under Phase B)
        bool i_released = false;
        if (!lastT && tid == 0) {
            unsigned* bg  = barr + (size_t)t * 160 + (size_t)g * 16;
            unsigned* btp = barr + (size_t)t * 160 + 128;
            unsigned* rl  = barr + (size_t)t * 160 + 144;
            unsigned old = __hip_atomic_fetch_add(bg, 1u, __ATOMIC_RELAXED,
                                                  __HIP_MEMORY_SCOPE_AGENT);
            if (old == gsize - 1u) {
                unsigned ot = __hip_atomic_fetch_add(btp, 1u, __ATOMIC_RELAXED,
                                                     __HIP_MEMORY_SCOPE_AGENT);
                if (ot == 7u) {
                    __hip_atomic_store(rl, 1u, __ATOMIC_RELAXED,
                                       __HIP_MEMORY_SCOPE_AGENT);
                    i_released = true;
                }
            }
        }

        // ======== Phase B: edge phase vs mask(t-1) + psc_rise update ========
        if (anyspk) {
#pragma unroll
            for (int k = 0; k < NQ; ++k) test4(q[k], w[k], smask, sacc);
            if (overflow) {
                for (int qq = q_lo + tid + NQ * BS; qq < q_hi; qq += BS)
                    test4(epack4[qq], ew4[qq], smask, sacc);
            }
        }
        __syncthreads();                          // S2: edge writes visible

        if (own) {
            float acc0 = sacc[tid * 4 + 0], acc1 = sacc[tid * 4 + 1];
            float acc2 = sacc[tid * 4 + 2], acc3 = sacc[tid * 4 + 3];
            sacc[tid * 4 + 0] = 0.f; sacc[tid * 4 + 1] = 0.f;  // re-zero own slots
            sacc[tid * 4 + 2] = 0.f; sacc[tid * 4 + 3] = 0.f;
            pr0 = pr0 * sd0 + (acc0 + xt.x) * pi0;   // new psc_rise
            pr1 = pr1 * sd1 + (acc1 + xt.y) * pi1;
            pr2 = pr2 * sd2 + (acc2 + xt.z) * pi2;
            pr3 = pr3 * sd3 + (acc3 + xt.w) * pi3;
            out[(size_t)t * N + n] = nz;             // in the barrier shadow
            zz = nz;
        }

        if (!lastT) {
            float4 xtn = own ? x_ext4[(size_t)(t + 1) * N + n] : zf;

            // ---- WAIT (release likely already set) + stage mask(t) ----
            if (tid == 0 && !i_released) {
                unsigned* rl = barr + (size_t)t * 160 + 144;
                while (!__hip_atomic_load(rl, __ATOMIC_RELAXED,
                                          __HIP_MEMORY_SCOPE_AGENT))
                    __builtin_amdgcn_s_sleep(1);
            }
            __syncthreads();                      // S3: released; zeroes done

            const unsigned long long* gm = (t & 1) ? mB : mA;
            unsigned long long m0 = 0ull, m1 = 0ull;
            if (tid < nmask)
                m0 = __hip_atomic_load(&gm[tid], __ATOMIC_RELAXED,
                                       __HIP_MEMORY_SCOPE_AGENT);
            if (tid + BS < nmask)
                m1 = __hip_atomic_load(&gm[tid + BS], __ATOMIC_RELAXED,
                                       __HIP_MEMORY_SCOPE_AGENT);
            if (tid < nmask) smask[tid] = m0;
            if (tid + BS < nmask) smask[tid + BS] = m1;
            anyspk = __syncthreads_or((m0 | m1) != 0ull ? 1 : 0);   // S4
            xt = xtn;
        }
    }
}

// ---------------- launch ----------------
extern "C" void kernel_launch(void* const* d_in, const int* in_sizes, int n_in,
                              void* d_out, int out_size, void* d_ws, size_t ws_size,
                              hipStream_t stream) {
    const float* w_rec = (const float*)d_in[0];
    const float* x_ext = (const float*)d_in[1];
    const float* v0    = (const float*)d_in[2];
    const float* v_th  = (const float*)d_in[3];
    const float* v_rst = (const float*)d_in[4];
    const float* t_rf  = (const float*)d_in[5];
    const float* decay = (const float*)d_in[6];
    const float* curf  = (const float*)d_in[7];
    const float* e_l   = (const float*)d_in[8];
    const float* aamps = (const float*)d_in[9];
    const float* adec  = (const float*)d_in[10];
    const float* syn_d = (const float*)d_in[11];
    const float* psc_i = (const float*)d_in[12];
    const int*   pre   = (const int*)d_in[13];
    const int*   post  = (const int*)d_in[14];
    const int*   rc    = (const int*)d_in[15];

    const int E = in_sizes[0];
    const int N = in_sizes[2];            // B == 1
    const int T = in_sizes[1] / (N * RR);
    const int nmask = (N + 63) / 64;
    const int NBK = (N + BKN - 1) / BKN;  // buckets == sim blocks (98)
    const int CH  = (E + NCH - 1) / NCH;
    const int nbar = 160 * T;             // per step: 8 group + top + release lines
    const int EP  = E + 4 * NBK;          // padded edge capacity

    // -------- workspace layout --------
    char* ws = (char*)d_ws;
    unsigned* epack  = (unsigned*)ws;                     ws += (size_t)EP * 4;
    float*    ew     = (float*)ws;                        ws += (size_t)EP * 4;
    unsigned long long* maskA = (unsigned long long*)ws;  ws += (size_t)nmask * 8;
    unsigned long long* maskB = (unsigned long long*)ws;  ws += (size_t)nmask * 8;
    int* ghist       = (int*)ws;                          ws += (size_t)NBK * NCH * 4;
    int* rtot        = (int*)ws;                          ws += (size_t)NBK * 4;
    int* ptot        = (int*)ws;                          ws += (size_t)NBK * 4;
    int* bstart      = (int*)ws;                          ws += (size_t)(NBK + 1) * 4;
    unsigned* barr   = (unsigned*)ws;                     /* +nbar*4 */

    // -------- setup (4 dispatches, contention-free) --------
    count_kernel<<<NCH, 256, 0, stream>>>(post, ghist, maskA, maskB, barr,
                                          E, CH, NBK, nmask, nbar);
    scanA_kernel<<<NBK, NCH, 0, stream>>>(ghist, rtot, ptot);
    scanB_kernel<<<1, 256, 0, stream>>>(rtot, ptot, bstart, epack, ew, NBK);
    fill_kernel<<<NCH, 256, 0, stream>>>(pre, post, rc, w_rec, ghist, bstart,
                                         epack, ew, E, CH, NBK);

    // -------- persistent sim: 98 blocks x 1024, 1 block/CU ----------------
    const size_t smbytes = (size_t)nmask * 8 + (size_t)BKN * RR * 4;  // ~28.5 KB
    sim_kernel<<<NBK, BS, smbytes, stream>>>(
        (const float4*)x_ext, v0, v_th, v_rst, t_rf, decay, curf, e_l,
        (const float2*)aamps, (const float2*)adec, syn_d, psc_i,
        (const uint4*)epack, (const float4*)ew, bstart, maskA, maskB, barr,
        (float*)d_out, N, nmask, T);
}

// Round 14
// 426.589 us; speedup vs baseline: 1.4897x; 1.4897x over previous
//
#include <hip/hip_runtime.h>

// Billeh column GLIF forward — persistent sim (R10 structure, best measured:
// 284us sim / 5.7us/step) + cheaper setup path.
//
// R13 post-mortem: 98x1024 regressed (9.2us/step) — arrivals were not the
// bottleneck; halving the grid halved mask-staging MALL parallelism and the
// 6-quad preload spilled. Reverted to 196x1024, BKN=512.
// This round targets the ~200us non-sim block (4 setup dispatches):
//  - AoS uint2 edge records {pre|rc<<18|lidx<<20, w}: fill does ONE 8B store
//    per edge (was two 4B stores to two far regions) -> ~halves fill's
//    touched-line count / write amplification,
//  - count/fill at 1024 threads x 256 chunks (was 256 x 512),
//  - sim preloads 8 uint4 (2 records each, 16 edges, 32 VGPR — same as R10).

constexpr int RR  = 4;
constexpr int BS  = 1024;               // threads per block (sim)
constexpr int BKN = 512;                // neurons per block (bucket size)
constexpr int BSH = 9;                  // log2(BKN)
constexpr int NCH = 256;                // partition chunks
constexpr int NQ  = 8;                  // preloaded uint4 units (2 records each)

// ---------------- pass 1: per-chunk bucket histogram (+ misc zeroing) ------
__global__ void count_kernel(const int* __restrict__ post, int* __restrict__ ghist,
                             unsigned long long* __restrict__ mA,
                             unsigned long long* __restrict__ mB,
                             unsigned* __restrict__ barr,
                             int E, int CH, int NBK, int nmask, int nbar) {
    __shared__ int h[256];                       // NBK <= 256
    for (int i = threadIdx.x; i < NBK; i += blockDim.x) h[i] = 0;
    __syncthreads();
    const int b = blockIdx.x, lo = b * CH, hi = min(lo + CH, E);
    for (int e = lo + threadIdx.x; e < hi; e += blockDim.x)
        atomicAdd(&h[post[e] >> BSH], 1);        // LDS atomic: block-local
    __syncthreads();
    for (int i = threadIdx.x; i < NBK; i += blockDim.x)
        ghist[i * NCH + b] = h[i];               // bucket-major
    int g = blockIdx.x * blockDim.x + threadIdx.x;
    int gs = gridDim.x * blockDim.x;
    for (int i = g; i < nmask; i += gs) { mA[i] = 0ull; mB[i] = 0ull; }
    for (int i = g; i < nbar; i += gs) barr[i] = 0u;
}

// ---------------- pass 2a: per-bucket exclusive scan over chunks -----------
__global__ void scanA_kernel(int* __restrict__ ghist, int* __restrict__ rtot,
                             int* __restrict__ ptot) {
    __shared__ int s[NCH];
    const int i = blockIdx.x, tid = threadIdx.x;
    int v = ghist[i * NCH + tid];
    s[tid] = v;
    __syncthreads();
    for (int off = 1; off < NCH; off <<= 1) {
        int t = (tid >= off) ? s[tid - off] : 0;
        __syncthreads();
        s[tid] += t;
        __syncthreads();
    }
    ghist[i * NCH + tid] = s[tid] - v;           // within-bucket exclusive
    if (tid == NCH - 1) {
        int tot = s[tid];
        rtot[i] = tot;
        ptot[i] = (tot + 3) & ~3;                // pad to x4 records (uint4-pair safe)
    }
}

// ---------------- pass 2b: scan padded totals -> bstart; zero pad slots ----
__global__ void scanB_kernel(const int* __restrict__ rtot, const int* __restrict__ ptot,
                             int* __restrict__ bstart,
                             uint2* __restrict__ ebuf, int NBK) {
    __shared__ int s[256];
    const int tid = threadIdx.x;
    int v = (tid < NBK) ? ptot[tid] : 0;
    s[tid] = v;
    __syncthreads();
    for (int off = 1; off < 256; off <<= 1) {
        int t = (tid >= off) ? s[tid - off] : 0;
        __syncthreads();
        s[tid] += t;
        __syncthreads();
    }
    if (tid < NBK) bstart[tid] = s[tid] - v;
    if (tid == NBK - 1) bstart[NBK] = s[tid];
    __syncthreads();
    if (tid < NBK) {                              // zero the <=3 pad records
        int base = bstart[tid];
        for (int k = base + rtot[tid]; k < base + ptot[tid]; ++k)
            ebuf[k] = make_uint2(0u, 0u);         // pre=0,w=0 -> adds 0.0, harmless
    }
}

// ---------------- pass 3: fill with block-local LDS cursors ----------------
// record: { pre(18b) | rc<<18 | lidx<<20 , w } — ONE 8B store per edge
__global__ void fill_kernel(const int* __restrict__ pre, const int* __restrict__ post,
                            const int* __restrict__ rc, const float* __restrict__ w,
                            const int* __restrict__ ghist, const int* __restrict__ bstart,
                            uint2* __restrict__ ebuf, int E, int CH, int NBK) {
    __shared__ int cur[256];
    const int b = blockIdx.x;
    for (int i = threadIdx.x; i < NBK; i += blockDim.x)
        cur[i] = bstart[i] + ghist[i * NCH + b];
    __syncthreads();
    const int lo = b * CH, hi = min(lo + CH, E);
    for (int e = lo + threadIdx.x; e < hi; e += blockDim.x) {
        int pn = post[e];
        int k = atomicAdd(&cur[pn >> BSH], 1);   // LDS atomic: block-local
        ebuf[k] = make_uint2((unsigned)pre[e] | ((unsigned)rc[e] << 18)
                             | ((unsigned)(pn & (BKN - 1)) << 20),
                             __float_as_uint(w[e]));
    }
}

// ---------------- persistent sim ----------------
// one uint4 = 2 records: {pk0, w0, pk1, w1}
__device__ __forceinline__ void test2(const uint4 u,
                                      const unsigned long long* smask,
                                      float* sacc) {
    unsigned a = u.x & 0x3FFFFu, b = u.z & 0x3FFFFu;
    if ((smask[a >> 6] >> (a & 63)) & 1ull)
        atomicAdd(&sacc[u.x >> 18], __uint_as_float(u.y));
    if ((smask[b >> 6] >> (b & 63)) & 1ull)
        atomicAdd(&sacc[u.z >> 18], __uint_as_float(u.w));
}

__global__ void __launch_bounds__(BS, 4)
sim_kernel(const float4* __restrict__ x_ext4,
           const float* __restrict__ v0,  const float* __restrict__ v_th,
           const float* __restrict__ v_rst, const float* __restrict__ t_rf,
           const float* __restrict__ decay, const float* __restrict__ curf,
           const float* __restrict__ e_l,
           const float2* __restrict__ aamps, const float2* __restrict__ adec,
           const float* __restrict__ syn_d4, const float* __restrict__ psc_i4,
           const uint4* __restrict__ ebuf4,
           const int* __restrict__ bstart,
           unsigned long long* __restrict__ mA, unsigned long long* __restrict__ mB,
           unsigned* __restrict__ barr,
           float* __restrict__ out, int N, int nmask, int T)
{
    extern __shared__ unsigned long long sdyn[];
    unsigned long long* smask = sdyn;            // nmask u64 (12.5 KB)
    float* sacc = (float*)(sdyn + nmask);        // BKN*4 floats (8 KB)
    const int tid = threadIdx.x;
    const int n = blockIdx.x * BKN + tid;        // owner mapping: tid < BKN
    const bool own = (tid < BKN) && (n < N);
    const unsigned nblk = gridDim.x;

    // ---- per-neuron state + params: registers for the whole run ----
    float psc0 = 0.f, psc1 = 0.f, psc2 = 0.f, psc3 = 0.f;
    float pr0 = 0.f, pr1 = 0.f, pr2 = 0.f, pr3 = 0.f;
    float vv = 0.f, rr_ = 0.f, zz = 0.f, a0 = 0.f, a1 = 0.f;
    float vth = 1.f, dvr = 0.f, trf = 0.f, dec = 0.f, cf = 0.f, el = 0.f;
    float aa0 = 0.f, aa1 = 0.f, ad0 = 0.f, ad1 = 0.f;
    if (own) {
        vv  = v0[n];
        vth = v_th[n];  dvr = v_rst[n] - vth;
        trf = t_rf[n];  dec = decay[n];
        cf  = curf[n];  el  = e_l[n];
        float2 aa = aamps[n]; aa0 = aa.x; aa1 = aa.y;
        float2 ad = adec[n];  ad0 = ad.x; ad1 = ad.y;
    }
    const float sd0 = syn_d4[0], sd1 = syn_d4[1], sd2 = syn_d4[2], sd3 = syn_d4[3];
    const float pi0 = psc_i4[0], pi1 = psc_i4[1], pi2 = psc_i4[2], pi3 = psc_i4[3];

    // ---- preload this thread's edges into REGISTERS (constant across t) ----
    const int u_lo = bstart[blockIdx.x] >> 1;    // uint4 units (2 records each)
    const int u_hi = bstart[blockIdx.x + 1] >> 1;
    const uint4 z4 = make_uint4(0u, 0u, 0u, 0u);
    const float4 zf = make_float4(0.f, 0.f, 0.f, 0.f);
    uint4 q[NQ];
#pragma unroll
    for (int k = 0; k < NQ; ++k) {
        int idx = u_lo + tid + k * BS;
        q[k] = (idx < u_hi) ? ebuf4[idx] : z4;
    }
    const bool overflow = (u_hi - u_lo) > NQ * BS;   // practically never

    const int g = blockIdx.x & 7;
    const unsigned gsize = (nblk - (unsigned)g + 7u) >> 3;

    // ---- prologue: zero LDS mask + accumulators; prefetch x(0) ----
    for (int i = tid; i < nmask; i += BS) smask[i] = 0ull;
    sacc[tid] = 0.f; sacc[tid + BS] = 0.f;
    float4 xt = own ? x_ext4[n] : zf;
    int anyspk = 0;
    __syncthreads();

    for (int t = 0; t < T; ++t) {
        // ======== Phase A: spike decision (OLD state only) + publish ========
        float nz = 0.f;
        if (own) {
            float npc0 = psc0 * sd0 + sd0 * pr0;   // OLD psc_rise, DT=1
            float npc1 = psc1 * sd1 + sd1 * pr1;
            float npc2 = psc2 * sd2 + sd2 * pr2;
            float npc3 = psc3 * sd3 + sd3 * pr3;
            float in_cur = npc0 + npc1 + npc2 + npc3;
            float asum = a0 + a1;                // OLD asc sum
            float nv = dec * vv + cf * (in_cur + asum + el) + zz * dvr;
            nz = (nv > vth) ? 1.f : 0.f;
            if (rr_ > 0.f) nz = 0.f;             // refractory mask (OLD r)
            rr_ = fmaxf(rr_ - 1.f + nz * trf, 0.f);
            a0 = ad0 * a0 + zz * aa0;            // asc update uses OLD z
            a1 = ad1 * a1 + zz * aa1;
            psc0 = npc0; psc1 = npc1; psc2 = npc2; psc3 = npc3;
            vv = nv;
        }
        const bool lastT = (t + 1 >= T);

        // publish mask(t) word (uncached store; one per wave)
        unsigned long long bal = __ballot(nz > 0.f);
        if (!lastT) {
            unsigned long long* gmo = (t & 1) ? mB : mA;
            if (own && (tid & 63) == 0)
                __hip_atomic_store(&gmo[n >> 6], bal, __ATOMIC_RELAXED,
                                   __HIP_MEMORY_SCOPE_AGENT);
            asm volatile("s_waitcnt vmcnt(0)" ::: "memory");
        }
        __syncthreads();                          // S1: all mask stores drained

        // non-blocking ARRIVAL (release chain completes under Phase B)
        bool i_released = false;
        if (!lastT && tid == 0) {
            unsigned* bg  = barr + (size_t)t * 160 + (size_t)g * 16;
            unsigned* btp = barr + (size_t)t * 160 + 128;
            unsigned* rl  = barr + (size_t)t * 160 + 144;
            unsigned old = __hip_atomic_fetch_add(bg, 1u, __ATOMIC_RELAXED,
                                                  __HIP_MEMORY_SCOPE_AGENT);
            if (old == gsize - 1u) {
                unsigned ot = __hip_atomic_fetch_add(btp, 1u, __ATOMIC_RELAXED,
                                                     __HIP_MEMORY_SCOPE_AGENT);
                if (ot == 7u) {
                    __hip_atomic_store(rl, 1u, __ATOMIC_RELAXED,
                                       __HIP_MEMORY_SCOPE_AGENT);
                    i_released = true;
                }
            }
        }

        // ======== Phase B: edge phase vs mask(t-1) + psc_rise update ========
        if (anyspk) {
#pragma unroll
            for (int k = 0; k < NQ; ++k) test2(q[k], smask, sacc);
            if (overflow) {
                for (int uu = u_lo + tid + NQ * BS; uu < u_hi; uu += BS)
                    test2(ebuf4[uu], smask, sacc);
            }
        }
        __syncthreads();                          // S2: edge writes visible

        if (own) {
            float acc0 = sacc[tid * 4 + 0], acc1 = sacc[tid * 4 + 1];
            float acc2 = sacc[tid * 4 + 2], acc3 = sacc[tid * 4 + 3];
            sacc[tid * 4 + 0] = 0.f; sacc[tid * 4 + 1] = 0.f;  // re-zero own slots
            sacc[tid * 4 + 2] = 0.f; sacc[tid * 4 + 3] = 0.f;
            pr0 = pr0 * sd0 + (acc0 + xt.x) * pi0;   // new psc_rise
            pr1 = pr1 * sd1 + (acc1 + xt.y) * pi1;
            pr2 = pr2 * sd2 + (acc2 + xt.z) * pi2;
            pr3 = pr3 * sd3 + (acc3 + xt.w) * pi3;
            out[(size_t)t * N + n] = nz;             // in the barrier shadow
            zz = nz;
        }

        if (!lastT) {
            float4 xtn = own ? x_ext4[(size_t)(t + 1) * N + n] : zf;

            // ---- WAIT (release likely already set) + stage mask(t) ----
            if (tid == 0 && !i_released) {
                unsigned* rl = barr + (size_t)t * 160 + 144;
                while (!__hip_atomic_load(rl, __ATOMIC_RELAXED,
                                          __HIP_MEMORY_SCOPE_AGENT))
                    __builtin_amdgcn_s_sleep(1);
            }
            __syncthreads();                      // S3: released; zeroes done

            const unsigned long long* gm = (t & 1) ? mB : mA;
            unsigned long long m0 = 0ull, m1 = 0ull;
            if (tid < nmask)
                m0 = __hip_atomic_load(&gm[tid], __ATOMIC_RELAXED,
                                       __HIP_MEMORY_SCOPE_AGENT);
            if (tid + BS < nmask)
                m1 = __hip_atomic_load(&gm[tid + BS], __ATOMIC_RELAXED,
                                       __HIP_MEMORY_SCOPE_AGENT);
            if (tid < nmask) smask[tid] = m0;
            if (tid + BS < nmask) smask[tid + BS] = m1;
            anyspk = __syncthreads_or((m0 | m1) != 0ull ? 1 : 0);   // S4
            xt = xtn;
        }
    }
}

// ---------------- launch ----------------
extern "C" void kernel_launch(void* const* d_in, const int* in_sizes, int n_in,
                              void* d_out, int out_size, void* d_ws, size_t ws_size,
                              hipStream_t stream) {
    const float* w_rec = (const float*)d_in[0];
    const float* x_ext = (const float*)d_in[1];
    const float* v0    = (const float*)d_in[2];
    const float* v_th  = (const float*)d_in[3];
    const float* v_rst = (const float*)d_in[4];
    const float* t_rf  = (const float*)d_in[5];
    const float* decay = (const float*)d_in[6];
    const float* curf  = (const float*)d_in[7];
    const float* e_l   = (const float*)d_in[8];
    const float* aamps = (const float*)d_in[9];
    const float* adec  = (const float*)d_in[10];
    const float* syn_d = (const float*)d_in[11];
    const float* psc_i = (const float*)d_in[12];
    const int*   pre   = (const int*)d_in[13];
    const int*   post  = (const int*)d_in[14];
    const int*   rc    = (const int*)d_in[15];

    const int E = in_sizes[0];
    const int N = in_sizes[2];            // B == 1
    const int T = in_sizes[1] / (N * RR);
    const int nmask = (N + 63) / 64;
    const int NBK = (N + BKN - 1) / BKN;  // buckets == sim blocks (196)
    const int CH  = (E + NCH - 1) / NCH;
    const int nbar = 160 * T;             // per step: 8 group + top + release lines
    const int EP  = E + 4 * NBK;          // padded edge capacity (records)

    // -------- workspace layout --------
    char* ws = (char*)d_ws;
    uint2* ebuf      = (uint2*)ws;                        ws += (size_t)EP * 8;
    unsigned long long* maskA = (unsigned long long*)ws;  ws += (size_t)nmask * 8;
    unsigned long long* maskB = (unsigned long long*)ws;  ws += (size_t)nmask * 8;
    int* ghist       = (int*)ws;                          ws += (size_t)NBK * NCH * 4;
    int* rtot        = (int*)ws;                          ws += (size_t)NBK * 4;
    int* ptot        = (int*)ws;                          ws += (size_t)NBK * 4;
    int* bstart      = (int*)ws;                          ws += (size_t)(NBK + 1) * 4;
    unsigned* barr   = (unsigned*)ws;                     /* +nbar*4 */

    // -------- setup (4 dispatches, contention-free) --------
    count_kernel<<<NCH, 1024, 0, stream>>>(post, ghist, maskA, maskB, barr,
                                           E, CH, NBK, nmask, nbar);
    scanA_kernel<<<NBK, NCH, 0, stream>>>(ghist, rtot, ptot);
    scanB_kernel<<<1, 256, 0, stream>>>(rtot, ptot, bstart, ebuf, NBK);
    fill_kernel<<<NCH, 1024, 0, stream>>>(pre, post, rc, w_rec, ghist, bstart,
                                          ebuf, E, CH, NBK);

    // -------- persistent sim: 196 blocks x 1024, 1 block/CU ----------------
    const size_t smbytes = (size_t)nmask * 8 + (size_t)BKN * RR * 4;  // ~20.5 KB
    sim_kernel<<<NBK, BS, smbytes, stream>>>(
        (const float4*)x_ext, v0, v_th, v_rst, t_rf, decay, curf, e_l,
        (const float2*)aamps, (const float2*)adec, syn_d, psc_i,
        (const uint4*)ebuf, bstart, maskA, maskB, barr,
        (float*)d_out, N, nmask, T);
}